// Round 17
// baseline (14156.017 us; speedup 1.0000x reference)
//
#include <hip/hip_runtime.h>

typedef unsigned short u16;
typedef unsigned int u32;
typedef __attribute__((ext_vector_type(8))) short bf16x8;
typedef __attribute__((ext_vector_type(4))) float f32x4;

#define SW(r) (((r) & 7) << 4)
#define RAW_BAR() { __builtin_amdgcn_s_barrier(); __builtin_amdgcn_sched_barrier(0); }
#define WAITV(N) { asm volatile("s_waitcnt vmcnt(" #N ")" ::: "memory"); __builtin_amdgcn_sched_barrier(0); }

__device__ __forceinline__ u16 f2bf(float f) {
  u32 x = __float_as_uint(f);
  x += 0x7fffu + ((x >> 16) & 1u);
  return (u16)(x >> 16);
}
__device__ __forceinline__ float bf2f(u16 h) { return __uint_as_float(((u32)h) << 16); }

__device__ __forceinline__ void gload_lds16(const void* g, void* l) {
  __builtin_amdgcn_global_load_lds(
      (const __attribute__((address_space(1))) u32*)g,
      (__attribute__((address_space(3))) u32*)l, 16, 0, 0);
}

__device__ __forceinline__ float fsigmoid(float x) { return 1.0f / (1.0f + __expf(-x)); }
__device__ __forceinline__ float ftanh(float x) {
  float a = fabsf(x);
  float t = __expf(-2.0f * a);
  float r = (1.0f - t) / (1.0f + t);
  return x < 0.0f ? -r : r;
}

// ---------------- prep: bf16 weight packs ----------------
// WihI/WhhI: gate-interleaved rows n = (c>>4)*64 + g*16 + (c&15), K=256 each.
__global__ void seqenc_prep_w(
    const float* __restrict__ w0, const float* __restrict__ w1,
    const float* __restrict__ w2, const float* __restrict__ w3,
    const float* __restrict__ wih, const float* __restrict__ whh,
    const float* __restrict__ bih, const float* __restrict__ bhh,
    const float* __restrict__ wq, const float* __restrict__ wk, const float* __restrict__ wv,
    const float* __restrict__ bq, const float* __restrict__ bk, const float* __restrict__ bv,
    const float* __restrict__ wout,
    u16* __restrict__ WihI, u16* __restrict__ WhhI, u16* __restrict__ Wqkv,
    u16* __restrict__ W0p, u16* __restrict__ W1b, u16* __restrict__ W2b,
    u16* __restrict__ W3b, u16* __restrict__ WoutB,
    float* __restrict__ bgI, float* __restrict__ bqkv)
{
  const long NIH = 262144L, NHH = 262144L, NQ = 196608L, N0P = 98304L;
  const long N1 = 262144L, N2 = 262144L, N3 = 131072L, NO = 65536L;
  const long NBG = 1024L, NBQ = 768L;
  const long TOT = NIH + NHH + NQ + N0P + N1 + N2 + N3 + NO + NBG + NBQ;
  for (long i = (long)blockIdx.x * blockDim.x + threadIdx.x; i < TOT;
       i += (long)gridDim.x * blockDim.x) {
    long j = i;
    if (j < NIH) {  // WihI[1024][256]
      long n = j >> 8, k = j & 255;
      int g = (int)((n & 63) >> 4);
      int c = (int)((n >> 6) * 16 + (n & 15));
      WihI[j] = f2bf(wih[(long)(g * 256 + c) * 256 + k]); continue;
    }
    j -= NIH;
    if (j < NHH) {  // WhhI[1024][256]
      long n = j >> 8, k = j & 255;
      int g = (int)((n & 63) >> 4);
      int c = (int)((n >> 6) * 16 + (n & 15));
      WhhI[j] = f2bf(whh[(long)(g * 256 + c) * 256 + k]); continue;
    }
    j -= NHH;
    if (j < NQ) {  // Wqkv[768][256]
      long n = j >> 8, k = j & 255;
      float v = (n < 256) ? wq[n * 256 + k] : (n < 512) ? wk[(n - 256) * 256 + k]
                                                        : wv[(n - 512) * 256 + k];
      Wqkv[j] = f2bf(v); continue;
    }
    j -= NQ;
    if (j < N0P) {  // W0p[512][192] zero-padded
      long n = j / 192, k = j - n * 192;
      W0p[j] = f2bf(k < 160 ? w0[n * 160 + k] : 0.0f); continue;
    }
    j -= N0P;
    if (j < N1) { W1b[j] = f2bf(w1[j]); continue; }
    j -= N1;
    if (j < N2) { W2b[j] = f2bf(w2[j]); continue; }
    j -= N2;
    if (j < N3) { W3b[j] = f2bf(w3[j]); continue; }
    j -= N3;
    if (j < NO) { WoutB[j] = f2bf(wout[j]); continue; }
    j -= NO;
    if (j < NBG) {  // bgI interleaved like WihI rows
      int g = (int)((j & 63) >> 4);
      int c = (int)((j >> 6) * 16 + (j & 15));
      long orig = g * 256 + c;
      bgI[j] = bih[orig] + bhh[orig]; continue;
    }
    j -= NBG;
    bqkv[j] = (j < 256) ? bq[j] : (j < 512) ? bk[j - 256] : bv[j - 512];
  }
}

// ---------------- prep: per-chunk padded concat input (t in [t0, t0+64)) ----------------
__global__ void seqenc_prep_x(
    const float* __restrict__ state, const float* __restrict__ actions,
    u16* __restrict__ XpadC, int t0)
{
  const int TOT = 32768 * 192;
  for (int i = blockIdx.x * blockDim.x + threadIdx.x; i < TOT;
       i += gridDim.x * blockDim.x) {
    int row = i / 192, col = i - row * 192;
    int tl = row >> 9, r = row & 511;
    int t = t0 + tl;
    int b = r >> 3, a = r & 7;
    float v = 0.0f;
    if (col < 128) v = state[((size_t)(b * 256 + t)) * 128 + col];
    else if (col < 160) v = actions[(((size_t)(b * 256 + t)) * 8 + a) * 32 + (col - 128)];
    XpadC[i] = f2bf(v);
  }
}

// ---------------- state init ----------------
__global__ void seqenc_init(const float* __restrict__ h0, const float* __restrict__ c0,
                            u16* __restrict__ hbuf, float* __restrict__ cbuf,
                            float* __restrict__ osum)
{
  int i = blockIdx.x * blockDim.x + threadIdx.x;
  if (i < 512 * 256) {
    hbuf[i] = f2bf(h0[i]);
    cbuf[i] = c0[i];
    osum[i] = 0.0f;
  }
}

// ---------------- unified GEMM (depth-2 pipelined, BK=64): modes 0/1/2 ----------------
__global__ __launch_bounds__(256) void seqenc_gemm(
    const u16* __restrict__ A1, const u16* __restrict__ A2, int K1, int lda,
    const u16* __restrict__ B, const float* __restrict__ bias,
    void* __restrict__ C, int ldc,
    int K, int N, int mode)
{
  __shared__ char As[2][16384];
  __shared__ char Bs[2][16384];
  const int tid = threadIdx.x;
  const int m0 = blockIdx.x * 128, n0 = blockIdx.y * 128;
  const int wid = tid >> 6, lane = tid & 63;
  const int wm = (wid >> 1) * 64, wn = (wid & 1) * 64;
  const int lr = lane & 15, kq = lane >> 4;
  f32x4 acc[4][4] = {};

  auto stage = [&](int tk, int buf) {
    int kt = tk << 6;
    const u16* Abase = (kt < K1) ? (A1 + kt) : (A2 + (kt - K1));
#pragma unroll
    for (int i2 = 0; i2 < 4; ++i2) {
      int q = i2 * 256 + tid;
      int r = q >> 3, cb = (q & 7) << 4;
      int scb = cb ^ SW(r);
      gload_lds16(Abase + (size_t)(m0 + r) * lda + (scb >> 1), As[buf] + q * 16);
      gload_lds16(B + (size_t)(n0 + r) * K + kt + (scb >> 1), Bs[buf] + q * 16);
    }
  };

  const int NT = K >> 6;
  stage(0, 0);
  int cur = 0;
  for (int t = 0; t < NT; ++t) {
    if (t + 1 < NT) { stage(t + 1, cur ^ 1); WAITV(8); }
    else { WAITV(0); }
    RAW_BAR();
#pragma unroll
    for (int ks = 0; ks < 2; ++ks) {
      bf16x8 af[4], bfr[4];
      int kb = ks * 64 + (kq << 4);
#pragma unroll
      for (int tt = 0; tt < 4; ++tt) {
        int ra = wm + tt * 16 + lr;
        af[tt] = *(const bf16x8*)(As[cur] + ra * 128 + (kb ^ SW(ra)));
        int rb = wn + tt * 16 + lr;
        bfr[tt] = *(const bf16x8*)(Bs[cur] + rb * 128 + (kb ^ SW(rb)));
      }
#pragma unroll
      for (int mt = 0; mt < 4; ++mt)
#pragma unroll
        for (int nt = 0; nt < 4; ++nt)
          acc[mt][nt] = __builtin_amdgcn_mfma_f32_16x16x32_bf16(af[mt], bfr[nt], acc[mt][nt], 0, 0, 0);
    }
    RAW_BAR();
    cur ^= 1;
  }

#pragma unroll
  for (int mt = 0; mt < 4; ++mt) {
#pragma unroll
    for (int nt = 0; nt < 4; ++nt) {
      int gn = n0 + wn + nt * 16 + lr;
      float bv = bias[gn];
#pragma unroll
      for (int rr = 0; rr < 4; ++rr) {
        int gm = m0 + wm + mt * 16 + (kq << 2) + rr;
        float v = acc[mt][nt][rr] + bv;
        if (mode == 1) v = fmaxf(v, 0.0f);
        if (mode == 2) ((float*)C)[(size_t)gm * ldc + gn] = v;
        else ((u16*)C)[(size_t)gm * ldc + gn] = f2bf(v);
      }
    }
  }
}

// ---------------- fused cell: gates + LSTM + qkv, m-partition (32 WGs x 16 rows) ----------------
// gates = xW (C-init) + h''@WhhI^T; LSTM -> h' (LDS restage); qkv = h'@Wqkv^T.
// Weights read per-WG but L2-resident (~900 KB unique/XCD). No cross-WG communication.
__global__ __launch_bounds__(256) void seqenc_cell(
    const u16* __restrict__ hbuf, const float* __restrict__ xWt,
    const u16* __restrict__ WhhI, const u16* __restrict__ Wqkv,
    const float* __restrict__ bqkvp,
    float* __restrict__ cbuf, u16* __restrict__ hq,
    u16* __restrict__ QKV, u16* __restrict__ vT)
{
  __shared__ __align__(16) char sh[8192];       // h' bf16 swz [16][512B]
  __shared__ __align__(16) u16 sqkv[16 * 784];  // qkv staging [16][784]
  const int tid = threadIdx.x;
  const int lane = tid & 63, w = tid >> 6;
  const int lr = lane & 15, kq = lane >> 4;
  const int r0 = blockIdx.x * 16;

  // A-fragments: h'' rows r0+lr, K=256
  bf16x8 af[8];
#pragma unroll
  for (int ks = 0; ks < 8; ++ks)
    af[ks] = *(const bf16x8*)(hbuf + (size_t)(r0 + lr) * 256 + ks * 32 + kq * 8);

  // gates: acc init from xW (x-projection, bias included), then += h''@Whh^T
  f32x4 acc[16];
#pragma unroll
  for (int j = 0; j < 16; ++j) {
    const float* xp = xWt + (size_t)(r0 + kq * 4) * 1024 + w * 256 + j * 16 + lr;
#pragma unroll
    for (int rr = 0; rr < 4; ++rr) acc[j][rr] = xp[(size_t)rr * 1024];
  }
#pragma unroll
  for (int j = 0; j < 16; ++j) {
    const u16* bp = WhhI + (size_t)(w * 256 + j * 16 + lr) * 256 + kq * 8;
#pragma unroll
    for (int ks = 0; ks < 8; ++ks) {
      bf16x8 bfr = *(const bf16x8*)(bp + ks * 32);
      acc[j] = __builtin_amdgcn_mfma_f32_16x16x32_bf16(af[ks], bfr, acc[j], 0, 0, 0);
    }
  }

  // LSTM epilogue: j = b2*4 + g -> gate g of cell w*64 + b2*16 + lr
#pragma unroll
  for (int b2 = 0; b2 < 4; ++b2) {
    int cell = w * 64 + b2 * 16 + lr;
#pragma unroll
    for (int rr = 0; rr < 4; ++rr) {
      int row = kq * 4 + rr;
      size_t gi = (size_t)(r0 + row) * 256 + cell;
      float i_ = fsigmoid(acc[b2 * 4 + 0][rr]);
      float f_ = fsigmoid(acc[b2 * 4 + 1][rr]);
      float g_ = ftanh(acc[b2 * 4 + 2][rr]);
      float o_ = fsigmoid(acc[b2 * 4 + 3][rr]);
      float cn = f_ * cbuf[gi] + i_ * g_;
      float hn = o_ * ftanh(cn);
      cbuf[gi] = cn;
      *(u16*)(sh + row * 512 + ((cell * 2) ^ SW(row))) = f2bf(hn);
    }
  }
  __syncthreads();

  // publish h' coalesced
  {
    int row = tid >> 4, c16 = (tid & 15) * 16;
    bf16x8 h0v = *(bf16x8*)(sh + row * 512 + ((c16 * 2) ^ SW(row)));
    bf16x8 h1v = *(bf16x8*)(sh + row * 512 + ((c16 * 2 + 16) ^ SW(row)));
    *(bf16x8*)(hq + (size_t)(r0 + row) * 256 + c16) = h0v;
    *(bf16x8*)(hq + (size_t)(r0 + row) * 256 + c16 + 8) = h1v;
  }

  // qkv: A-fragments from h' (LDS), B streamed from Wqkv, acc init = bias
  bf16x8 af2[8];
#pragma unroll
  for (int ks = 0; ks < 8; ++ks)
    af2[ks] = *(const bf16x8*)(sh + lr * 512 + ((ks * 64 + kq * 16) ^ SW(lr)));

  f32x4 acc2[12];
#pragma unroll
  for (int j = 0; j < 12; ++j) {
    float bv = bqkvp[w * 192 + j * 16 + lr];
    acc2[j][0] = bv; acc2[j][1] = bv; acc2[j][2] = bv; acc2[j][3] = bv;
  }
#pragma unroll
  for (int j = 0; j < 12; ++j) {
    const u16* bp = Wqkv + (size_t)(w * 192 + j * 16 + lr) * 256 + kq * 8;
#pragma unroll
    for (int ks = 0; ks < 8; ++ks) {
      bf16x8 bfr = *(const bf16x8*)(bp + ks * 32);
      acc2[j] = __builtin_amdgcn_mfma_f32_16x16x32_bf16(af2[ks], bfr, acc2[j], 0, 0, 0);
    }
  }
  // stage qkv rows to LDS
#pragma unroll
  for (int j = 0; j < 12; ++j) {
    int col = w * 192 + j * 16 + lr;
#pragma unroll
    for (int rr = 0; rr < 4; ++rr)
      sqkv[(kq * 4 + rr) * 784 + col] = f2bf(acc2[j][rr]);
  }
  __syncthreads();

  // publish q|k coalesced (cols 0..512 of QKV rows)
#pragma unroll
  for (int k2 = 0; k2 < 4; ++k2) {
    int ch = tid + k2 * 256;
    int row = ch >> 6, cb = (ch & 63) * 8;
    *(bf16x8*)(QKV + (size_t)(r0 + row) * 768 + cb) = *(bf16x8*)(sqkv + row * 784 + cb);
  }
  // publish vT: col c = tid, 16 key-rows contiguous
  {
    int c = tid;
    u16 tmp[16];
#pragma unroll
    for (int row = 0; row < 16; ++row)
      tmp[row] = sqkv[row * 784 + 512 + c];
    *(bf16x8*)(vT + (size_t)c * 512 + r0) = *(bf16x8*)tmp;
    *(bf16x8*)(vT + (size_t)c * 512 + r0 + 8) = *(bf16x8*)(tmp + 8);
  }
}

// ---------------- attention: 32 WGs x 16 rows; pipelined k/v loads ----------------
__global__ __launch_bounds__(512) void seqenc_attn(
    const u16* __restrict__ QKV, const u16* __restrict__ vT,
    const u16* __restrict__ hq, u16* __restrict__ hbuf, float* __restrict__ osum)
{
  __shared__ float scratch[16 * 516];
  __shared__ char spb[16 * 1024];
  const int tid = threadIdx.x;
  const int lane = tid & 63, wid = tid >> 6;
  const int lr = lane & 15, kq = lane >> 4;
  const int r0 = blockIdx.x * 16;

  u16 hql[2][4];
#pragma unroll
  for (int nt = 0; nt < 2; ++nt) {
    const int d0 = wid * 32 + nt * 16;
#pragma unroll
    for (int rr = 0; rr < 4; ++rr)
      hql[nt][rr] = hq[(size_t)(r0 + kq * 4 + rr) * 256 + d0 + lr];
  }

  bf16x8 vfp[8];

  {
    bf16x8 qf[8];
#pragma unroll
    for (int ks = 0; ks < 8; ++ks)
      qf[ks] = *(const bf16x8*)(QKV + (size_t)(r0 + lr) * 768 + ks * 32 + (kq << 3));
    bf16x8 kf[2][8];
    {
      const u16* bp = QKV + (size_t)(wid * 64 + lr) * 768 + 256 + (kq << 3);
#pragma unroll
      for (int ks = 0; ks < 8; ++ks) kf[0][ks] = *(const bf16x8*)(bp + ks * 32);
    }
#pragma unroll
    for (int nt = 0; nt < 4; ++nt) {
      if (nt + 1 < 4) {
        const u16* bpn = QKV + (size_t)(wid * 64 + (nt + 1) * 16 + lr) * 768 + 256 + (kq << 3);
#pragma unroll
        for (int ks = 0; ks < 8; ++ks) kf[(nt + 1) & 1][ks] = *(const bf16x8*)(bpn + ks * 32);
      } else {
        const u16* vp0 = vT + (size_t)(wid * 32 + lr) * 512 + (kq << 3);
#pragma unroll
        for (int ks = 0; ks < 8; ++ks) vfp[ks] = *(const bf16x8*)(vp0 + ks * 32);
      }
      f32x4 a4 = {0.0f, 0.0f, 0.0f, 0.0f};
#pragma unroll
      for (int ks = 0; ks < 8; ++ks)
        a4 = __builtin_amdgcn_mfma_f32_16x16x32_bf16(qf[ks], kf[nt & 1][ks], a4, 0, 0, 0);
      const int key0 = wid * 64 + nt * 16;
#pragma unroll
      for (int rr = 0; rr < 4; ++rr)
        scratch[(kq * 4 + rr) * 516 + key0 + lr] = a4[rr];
    }
  }
  __syncthreads();

  {
    int r = tid >> 5, l32 = tid & 31;
    float vals[16];
    float m = -3.4e38f;
#pragma unroll
    for (int j2 = 0; j2 < 16; ++j2) {
      vals[j2] = scratch[r * 516 + l32 + j2 * 32];
      m = fmaxf(m, vals[j2]);
    }
#pragma unroll
    for (int s2 = 16; s2 > 0; s2 >>= 1) m = fmaxf(m, __shfl_xor(m, s2, 32));
    float sum = 0.0f;
#pragma unroll
    for (int j2 = 0; j2 < 16; ++j2) {
      vals[j2] = __expf((vals[j2] - m) * 0.0625f);
      sum += vals[j2];
    }
#pragma unroll
    for (int s2 = 16; s2 > 0; s2 >>= 1) sum += __shfl_xor(sum, s2, 32);
    float inv = 1.0f / sum;
#pragma unroll
    for (int j2 = 0; j2 < 16; ++j2) {
      int c = l32 + j2 * 32;
      *(u16*)(spb + r * 1024 + ((c * 2) ^ SW(r))) = f2bf(vals[j2] * inv);
    }
  }
  __syncthreads();

  {
    bf16x8 pf[16];
#pragma unroll
    for (int ks = 0; ks < 16; ++ks)
      pf[ks] = *(const bf16x8*)(spb + lr * 1024 + ((ks * 64 + (kq << 4)) ^ SW(lr)));
    const u16* vp = vT + (size_t)(wid * 32 + lr) * 512 + (kq << 3);
    bf16x8 vfb[8];
#pragma unroll
    for (int ks = 0; ks < 8; ++ks) vfb[ks] = *(const bf16x8*)(vp + 256 + ks * 32);
    f32x4 a0 = {0.0f, 0.0f, 0.0f, 0.0f};
#pragma unroll
    for (int ks = 0; ks < 8; ++ks)
      a0 = __builtin_amdgcn_mfma_f32_16x16x32_bf16(pf[ks], vfp[ks], a0, 0, 0, 0);
#pragma unroll
    for (int ks = 0; ks < 8; ++ks) vfp[ks] = *(const bf16x8*)(vp + 8192 + ks * 32);
#pragma unroll
    for (int ks = 0; ks < 8; ++ks)
      a0 = __builtin_amdgcn_mfma_f32_16x16x32_bf16(pf[8 + ks], vfb[ks], a0, 0, 0, 0);
#pragma unroll
    for (int ks = 0; ks < 8; ++ks) vfb[ks] = *(const bf16x8*)(vp + 8448 + ks * 32);
    f32x4 a1 = {0.0f, 0.0f, 0.0f, 0.0f};
#pragma unroll
    for (int ks = 0; ks < 8; ++ks)
      a1 = __builtin_amdgcn_mfma_f32_16x16x32_bf16(pf[ks], vfp[ks], a1, 0, 0, 0);
#pragma unroll
    for (int ks = 0; ks < 8; ++ks)
      a1 = __builtin_amdgcn_mfma_f32_16x16x32_bf16(pf[8 + ks], vfb[ks], a1, 0, 0, 0);
#pragma unroll
    for (int rr = 0; rr < 4; ++rr) {
      int row = kq * 4 + rr;
      int col0 = wid * 32 + lr;
      size_t gi0 = (size_t)(r0 + row) * 256 + col0;
      float hn0 = bf2f(hql[0][rr]) + a0[rr];
      hbuf[gi0] = f2bf(hn0);
      osum[gi0] += hn0;
      size_t gi1 = gi0 + 16;
      float hn1 = bf2f(hql[1][rr]) + a1[rr];
      hbuf[gi1] = f2bf(hn1);
      osum[gi1] += hn1;
    }
  }
}

// ---------------- osum/256 -> bf16 ----------------
__global__ void seqenc_conv(const float* __restrict__ osum, u16* __restrict__ ob)
{
  int i = blockIdx.x * blockDim.x + threadIdx.x;
  if (i < 512 * 256) ob[i] = f2bf(osum[i] * (1.0f / 256.0f));
}

extern "C" void kernel_launch(void* const* d_in, const int* in_sizes, int n_in,
                              void* d_out, int out_size, void* d_ws, size_t ws_size,
                              hipStream_t stream) {
  (void)in_sizes; (void)n_in; (void)out_size; (void)ws_size;
  const float* state = (const float*)d_in[0];
  const float* actions = (const float*)d_in[1];
  const float* h0 = (const float*)d_in[2];
  const float* c0 = (const float*)d_in[3];
  const float* w0 = (const float*)d_in[4];
  const float* b0 = (const float*)d_in[5];
  const float* w1 = (const float*)d_in[6];
  const float* b1 = (const float*)d_in[7];
  const float* w2 = (const float*)d_in[8];
  const float* b2 = (const float*)d_in[9];
  const float* w3 = (const float*)d_in[10];
  const float* b3 = (const float*)d_in[11];
  const float* wih = (const float*)d_in[12];
  const float* whh = (const float*)d_in[13];
  const float* bih = (const float*)d_in[14];
  const float* bhh = (const float*)d_in[15];
  const float* wq = (const float*)d_in[16];
  const float* bq = (const float*)d_in[17];
  const float* wk = (const float*)d_in[18];
  const float* bk = (const float*)d_in[19];
  const float* wv = (const float*)d_in[20];
  const float* bv = (const float*)d_in[21];
  const float* wout = (const float*)d_in[22];
  const float* bout = (const float*)d_in[23];

  char* ws = (char*)d_ws;
  size_t off = 0;
  auto take = [&](size_t bytes) {
    off = (off + 255) & ~(size_t)255;
    char* p = ws + off;
    off += bytes;
    return p;
  };
  u16* XpadC = (u16*)take(32768UL * 192 * 2);
  u16* ping  = (u16*)take(32768UL * 512 * 2);   // MLP intermediate; dead after MLP
  u16* pong  = (u16*)take(32768UL * 512 * 2);   // MLP intermediate; dead after MLP
  float* xW  = (float*)ping;                    // ALIAS: 32-step f32 window [16384][1024]
  u16* X4    = (u16*)take(131072UL * 256 * 2);
  u16* W0p   = (u16*)take(512UL * 192 * 2);
  u16* W1b   = (u16*)take(512UL * 512 * 2);
  u16* W2b   = (u16*)take(512UL * 512 * 2);
  u16* W3b   = (u16*)take(256UL * 512 * 2);
  u16* WihI  = (u16*)take(1024UL * 256 * 2);
  u16* WhhI  = (u16*)take(1024UL * 256 * 2);
  u16* Wqkv  = (u16*)take(768UL * 256 * 2);
  u16* WoutB = (u16*)take(256UL * 256 * 2);
  float* bgI   = (float*)take(1024UL * 4);
  float* bqkvp = (float*)take(768UL * 4);
  u16* QKV   = (u16*)take(512UL * 768 * 2);
  u16* vT    = (u16*)take(256UL * 512 * 2);
  u16* hbuf  = (u16*)take(512UL * 256 * 2);   // h'' (post-attn), input to cell
  u16* hq    = (u16*)take(512UL * 256 * 2);   // h' (post-lstm), input to attn
  float* cbuf  = (float*)take(512UL * 256 * 4);
  float* osum  = (float*)take(512UL * 256 * 4);
  u16* ob    = (u16*)take(512UL * 256 * 2);

  seqenc_prep_w<<<1024, 256, 0, stream>>>(w0, w1, w2, w3, wih, whh, bih, bhh,
                                          wq, wk, wv, bq, bk, bv, wout,
                                          WihI, WhhI, Wqkv, W0p, W1b, W2b, W3b, WoutB, bgI, bqkvp);
  seqenc_init<<<512, 256, 0, stream>>>(h0, c0, hbuf, cbuf, osum);

  const int CM = 32768;
  for (int c = 0; c < 4; ++c) {
    u16* x4c = X4 + (size_t)c * CM * 256;
    seqenc_prep_x<<<2048, 256, 0, stream>>>(state, actions, XpadC, c * 64);
    seqenc_gemm<<<dim3(CM / 128, 4), 256, 0, stream>>>(XpadC, XpadC, 192, 192, W0p, b0, ping, 512, 192, 512, 1);
    seqenc_gemm<<<dim3(CM / 128, 4), 256, 0, stream>>>(ping, ping, 512, 512, W1b, b1, pong, 512, 512, 512, 1);
    seqenc_gemm<<<dim3(CM / 128, 4), 256, 0, stream>>>(pong, pong, 512, 512, W2b, b2, ping, 512, 512, 512, 1);
    seqenc_gemm<<<dim3(CM / 128, 2), 256, 0, stream>>>(ping, ping, 512, 512, W3b, b3, x4c, 256, 512, 256, 0);
  }

  // recurrent loop in 8 windows of 32 steps; bulk x-projection per window
  for (int c = 0; c < 8; ++c) {
    const u16* x4w = X4 + (size_t)c * 32 * 512 * 256;
    seqenc_gemm<<<dim3(128, 8), 256, 0, stream>>>(x4w, x4w, 256, 256, WihI, bgI, xW, 1024, 256, 1024, 2);
    for (int tt = 0; tt < 32; ++tt) {
      const float* xWt = xW + (size_t)tt * 512 * 1024;
      seqenc_cell<<<32, 256, 0, stream>>>(hbuf, xWt, WhhI, Wqkv, bqkvp, cbuf, hq, QKV, vT);
      seqenc_attn<<<32, 512, 0, stream>>>(QKV, vT, hq, hbuf, osum);
    }
  }

  seqenc_conv<<<512, 256, 0, stream>>>(osum, ob);
  seqenc_gemm<<<dim3(4, 2), 256, 0, stream>>>(ob, ob, 256, 256, WoutB, bout, d_out, 256, 256, 256, 2);
}